// Round 6
// baseline (52.266 us; speedup 1.0000x reference)
//
#include <hip/hip_runtime.h>
#include <hip/hip_bf16.h>
#include <math.h>

// Problem dims (fixed per reference)
#define B_DIM 32
#define C_DIM 256
#define K_DIM 32
#define N_DIM 4096   // 64*64
#define NSLICE 32    // 128-px slices
#define RS 66        // padded dword stride per c-pair row (16 rows/tile)

typedef short v8s __attribute__((ext_vector_type(8)));   // 8 bf16
typedef float v4f __attribute__((ext_vector_type(4)));   // MFMA acc

// ws float offsets — every slot overwritten each call, no zeroing, no atomics
//   [0,     32)      c2   [K]
//   [32,    4128)    cw_bf16 [K][C] as u16 (16 KB)
//   [4128,  266272)  Spart [B][32][C]
//   [266272,299040)  a_part[B][32][K]
#define WS_C2    0
#define WS_CWB   32
#define WS_SPART 4128
#define WS_APART 266272

__global__ __launch_bounds__(64)
void ce_prep(const float* __restrict__ cw, float* __restrict__ ws) {
    const int k    = blockIdx.x;    // 0..31
    const int lane = threadIdx.x;   // 0..63
    float4 v = ((const float4*)(cw + (size_t)k * C_DIM))[lane];
    union { unsigned short s[4]; uint2 d; } o;
    union { __hip_bfloat16 h; unsigned short u; } cv;
    cv.h = __float2bfloat16(v.x); o.s[0] = cv.u;
    cv.h = __float2bfloat16(v.y); o.s[1] = cv.u;
    cv.h = __float2bfloat16(v.z); o.s[2] = cv.u;
    cv.h = __float2bfloat16(v.w); o.s[3] = cv.u;
    unsigned short* cwb = (unsigned short*)(ws + WS_CWB);
    ((uint2*)(cwb + (size_t)k * C_DIM))[lane] = o.d;

    float sq = 0.f;
    sq = fmaf(v.x, v.x, sq); sq = fmaf(v.y, v.y, sq);
    sq = fmaf(v.z, v.z, sq); sq = fmaf(v.w, v.w, sq);
    sq += __shfl_xor(sq, 1);
    sq += __shfl_xor(sq, 2);
    sq += __shfl_xor(sq, 4);
    sq += __shfl_xor(sq, 8);
    sq += __shfl_xor(sq, 16);
    sq += __shfl_xor(sq, 32);
    if (lane == 0) ws[WS_C2 + k] = sq;
}

__global__ __launch_bounds__(256, 4)
void ce_main(const float* __restrict__ x,
             const float* __restrict__ scale,
             const float* __restrict__ ws_ro,
             float* __restrict__ Spart,
             float* __restrict__ a_part) {
    __shared__ float buf[2][4][16 * RS];   // 33 KB staging; reused as comb after loop
    __shared__ float sA[4][128];           // per-wave S partials (c-local)
    __shared__ float awv[4][K_DIM];        // per-wave a partials
    __shared__ float f2s[4][64];           // per-wave f2 exchange

    const int tid   = threadIdx.x;
    const int wave  = tid >> 6;     // = 2*p + h
    const int lane  = tid & 63;
    const int p     = wave >> 1;    // px group (64 px each)
    const int hh    = wave & 1;     // c half (128 c each)
    const int g     = lane >> 4;
    const int m     = lane & 15;
    const int slice = blockIdx.x;   // 0..31 (128 px)
    const int b     = blockIdx.y;   // 0..31

    const float* xw   = x + (size_t)b * C_DIM * N_DIM + slice * 128 + p * 64;
    const uint4* cwb4 = (const uint4*)(ws_ro + WS_CWB);
    const float* c2p  = ws_ro + WS_C2;
    const int cbase   = hh << 7;

    float* b0 = &buf[0][wave][0];
    float* b1 = &buf[1][wave][0];

    v4f acc[2][4];
    #pragma unroll
    for (int u = 0; u < 2; ++u)
        #pragma unroll
        for (int t = 0; t < 4; ++t) acc[u][t] = (v4f){0.f, 0.f, 0.f, 0.f};

    float f2 = 0.f;
    float sLo[4], sHi[4];
    float fA[16], fB[16];

    // A-frag prefetch (cw bf16): k = 16u+m, c = cbase + 8g..8g+7
    uint4 af0 = cwb4[m * 32 + 16 * hh + g];
    uint4 af1 = cwb4[(16 + m) * 32 + 16 * hh + g];

    // stage c-step 0
    #pragma unroll
    for (int i = 0; i < 16; ++i) {
        fA[i] = xw[(size_t)(cbase + 2 * i) * N_DIM + lane];
        fB[i] = xw[(size_t)(cbase + 2 * i + 1) * N_DIM + lane];
    }
    #pragma unroll
    for (int i = 0; i < 16; ++i) {
        f2 = fmaf(fA[i], fA[i], f2);
        f2 = fmaf(fB[i], fB[i], f2);
        union { __hip_bfloat16 h; unsigned short u; } lo, hi;
        lo.h = __float2bfloat16(fA[i]);
        hi.h = __float2bfloat16(fB[i]);
        ((unsigned*)b0)[i * RS + lane] = ((unsigned)hi.u << 16) | lo.u;
    }

    #pragma unroll
    for (int s = 0; s < 4; ++s) {
        float* cb = (s & 1) ? b1 : b0;
        float* nb = (s & 1) ? b0 : b1;

        uint4 naf0, naf1;
        if (s < 3) {
            naf0 = cwb4[m * 32 + 16 * hh + 4 * (s + 1) + g];
            naf1 = cwb4[(16 + m) * 32 + 16 * hh + 4 * (s + 1) + g];
            #pragma unroll
            for (int i = 0; i < 16; ++i) {
                fA[i] = xw[(size_t)(cbase + 32 * (s + 1) + 2 * i) * N_DIM + lane];
                fB[i] = xw[(size_t)(cbase + 32 * (s + 1) + 2 * i + 1) * N_DIM + lane];
            }
        }

        // B-frags + 8 MFMA: D[k][px] += cw[k][c] * f[c][px]
        #pragma unroll
        for (int t = 0; t < 4; ++t) {
            union { unsigned d[4]; v8s v; } fb;
            #pragma unroll
            for (int h2 = 0; h2 < 4; ++h2)
                fb.d[h2] = ((const unsigned*)cb)[(4 * g + h2) * RS + 16 * t + m];
            union { uint4 u; v8s v; } a0, a1;
            a0.u = af0; a1.u = af1;
            acc[0][t] = __builtin_amdgcn_mfma_f32_16x16x32_bf16(a0.v, fb.v, acc[0][t], 0, 0, 0);
            acc[1][t] = __builtin_amdgcn_mfma_f32_16x16x32_bf16(a1.v, fb.v, acc[1][t], 0, 0, 0);
        }

        // S row sums: lane owns c-pair row m, dword chunk 16g..16g+15
        {
            float aLo = 0.f, aHi = 0.f;
            #pragma unroll
            for (int q = 0; q < 8; ++q) {
                uint2 w = ((const uint2*)cb)[33 * m + 8 * g + q];
                aLo += __uint_as_float(w.x << 16) + __uint_as_float(w.y << 16);
                aHi += __uint_as_float(w.x & 0xffff0000u) + __uint_as_float(w.y & 0xffff0000u);
            }
            aLo += __shfl_xor(aLo, 16); aLo += __shfl_xor(aLo, 32);
            aHi += __shfl_xor(aHi, 16); aHi += __shfl_xor(aHi, 32);
            sLo[s] = aLo; sHi[s] = aHi;
        }

        if (s < 3) {
            #pragma unroll
            for (int i = 0; i < 16; ++i) {
                f2 = fmaf(fA[i], fA[i], f2);
                f2 = fmaf(fB[i], fB[i], f2);
                union { __hip_bfloat16 h; unsigned short u; } lo, hi;
                lo.h = __float2bfloat16(fA[i]);
                hi.h = __float2bfloat16(fB[i]);
                ((unsigned*)nb)[i * RS + lane] = ((unsigned)hi.u << 16) | lo.u;
            }
            af0 = naf0; af1 = naf1;
        }
    }

    __syncthreads();  // all staging-buffer reads complete; buf becomes comb

    // give away the two t-tiles the partner wave will finish
    float* comb = &buf[0][0][0];
    #pragma unroll
    for (int u = 0; u < 2; ++u)
        #pragma unroll
        for (int d = 0; d < 2; ++d) {
            int t = 2 * (1 - hh) + d;
            #pragma unroll
            for (int r = 0; r < 4; ++r)
                comb[((((p * 4 + t) * 2 + u) * 4 + r) << 6) + lane] = acc[u][t][r];
        }
    f2s[wave][lane] = f2;
    if (g == 0) {
        #pragma unroll
        for (int s = 0; s < 4; ++s) {
            sA[wave][32 * s + 2 * m]     = sLo[s];
            sA[wave][32 * s + 2 * m + 1] = sHi[s];
        }
    }
    __syncthreads();

    // softmax on kept t-tiles (t = 2*hh + d), with combined dot and f2
    float c2v[2][4], scv[2][4];
    #pragma unroll
    for (int u = 0; u < 2; ++u)
        #pragma unroll
        for (int r = 0; r < 4; ++r) {
            int k = 16 * u + 4 * g + r;
            c2v[u][r] = c2p[k];
            scv[u][r] = scale[k];
        }

    float aacc[2][4] = {{0.f,0.f,0.f,0.f},{0.f,0.f,0.f,0.f}};
    #pragma unroll
    for (int d = 0; d < 2; ++d) {
        const int t = 2 * hh + d;
        float f2t = f2s[2 * p][16 * t + m] + f2s[2 * p + 1][16 * t + m];
        float L[2][4];
        float mx = -1e30f;
        #pragma unroll
        for (int u = 0; u < 2; ++u)
            #pragma unroll
            for (int r = 0; r < 4; ++r) {
                float dv = acc[u][t][r] +
                           comb[((((p * 4 + t) * 2 + u) * 4 + r) << 6) + lane];
                float d2 = f2t + c2v[u][r] - 2.f * dv;
                float dist = sqrtf(fmaxf(d2, 0.f));
                float Lv = -dist * scv[u][r];
                L[u][r] = Lv;
                mx = fmaxf(mx, Lv);
            }
        mx = fmaxf(mx, __shfl_xor(mx, 16));
        mx = fmaxf(mx, __shfl_xor(mx, 32));
        float e[2][4], ss = 0.f;
        #pragma unroll
        for (int u = 0; u < 2; ++u)
            #pragma unroll
            for (int r = 0; r < 4; ++r) {
                e[u][r] = __expf(L[u][r] - mx);
                ss += e[u][r];
            }
        ss += __shfl_xor(ss, 16);
        ss += __shfl_xor(ss, 32);
        float inv = 1.f / ss;
        #pragma unroll
        for (int u = 0; u < 2; ++u)
            #pragma unroll
            for (int r = 0; r < 4; ++r)
                aacc[u][r] = fmaf(e[u][r], inv, aacc[u][r]);
    }

    // reduce a over the 16 pixels (m) per t-column
    #pragma unroll
    for (int u = 0; u < 2; ++u)
        #pragma unroll
        for (int r = 0; r < 4; ++r) {
            float v = aacc[u][r];
            v += __shfl_xor(v, 1);
            v += __shfl_xor(v, 2);
            v += __shfl_xor(v, 4);
            v += __shfl_xor(v, 8);
            if (m == 0) awv[wave][16 * u + 4 * g + r] = v;
        }
    __syncthreads();

    const int ch = tid >> 7, cl = tid & 127;
    Spart[((size_t)b * NSLICE + slice) * C_DIM + tid] = sA[ch][cl] + sA[2 + ch][cl];
    if (tid < K_DIM)
        a_part[((size_t)b * NSLICE + slice) * K_DIM + tid] =
            awv[0][tid] + awv[1][tid] + awv[2][tid] + awv[3][tid];
}

__global__ void ce_final(float* __restrict__ out,
                         const float* __restrict__ cw,
                         const float* __restrict__ Spart,
                         const float* __restrict__ a_part) {
    __shared__ float asum[K_DIM];
    const int b = blockIdx.x;
    const int c = threadIdx.x;

    if (c < K_DIM) {
        float a = 0.f;
        #pragma unroll
        for (int s = 0; s < NSLICE; ++s)
            a += a_part[((size_t)b * NSLICE + s) * K_DIM + c];
        asum[c] = a;
    }
    __syncthreads();

    float S = 0.f;
    #pragma unroll
    for (int s = 0; s < NSLICE; ++s)
        S += Spart[((size_t)b * NSLICE + s) * C_DIM + c];

    float acc2 = 0.f;
    #pragma unroll
    for (int k = 0; k < K_DIM; ++k)
        acc2 = fmaf(asum[k], cw[k * C_DIM + c], acc2);  // coalesced over c
    out[b * C_DIM + c] = (S - acc2) * (1.0f / (float)K_DIM);
}

extern "C" void kernel_launch(void* const* d_in, const int* in_sizes, int n_in,
                              void* d_out, int out_size, void* d_ws, size_t ws_size,
                              hipStream_t stream) {
    const float* x     = (const float*)d_in[0];
    const float* cw    = (const float*)d_in[1];
    const float* scale = (const float*)d_in[2];
    float* out = (float*)d_out;
    float* ws  = (float*)d_ws;

    ce_prep<<<K_DIM, 64, 0, stream>>>(cw, ws);

    dim3 grid(NSLICE, B_DIM);
    ce_main<<<grid, 256, 0, stream>>>(x, scale, ws,
                                      ws + WS_SPART, ws + WS_APART);

    ce_final<<<B_DIM, 256, 0, stream>>>(out, cw,
                                        ws + WS_SPART, ws + WS_APART);
}